// Round 2
// baseline (186167.090 us; speedup 1.0000x reference)
//
#include <hip/hip_runtime.h>
#include <hip/hip_fp16.h>

// SpellerModel round 2: single persistent cooperative kernel.
// 256 WGs x 512 threads, 5 stages/step, two-level global barrier.
// LSTM GEMM: per-WG 16x32 tile, K-split 16, 4x4 register tiles (2 B/FMA LDS).

#define BB 64
#define TT 200
#define SS 400
#define VV 34
#define EE 256
#define HH 512
#define KD 256
#define NSTEP 201
#define NWG 256
#define TPB 512

// workspace float offsets
#define OFF_X1   0          // [2][64][1024]  (emb|ctx|h1)
#define OFF_X2   131072     // [2][64][1024]  (h1|h2)
#define OFF_X3   262144     // [2][64][1024]  (h2|h3)
#define OFF_C1   393216     // [64][512]
#define OFF_C2   425984
#define OFF_C3   458752
#define OFF_Q    491520     // [64][256]
#define OFF_LACC 507904     // [64]
#define OFF_BS1  507968     // [2048] bih+bhh
#define OFF_BS2  510016
#define OFF_BS3  512064
#define OFF_WVT  514112     // [512*34]
#define OFF_BAR  531520     // 1024 uints
#define FP16_BYTE_OFF 2134016u

struct SMem {
  union U {
    struct { float xa[2][16][132]; float wa[2][32][132]; } s;   // 50688 B
    float red[512][17];                                          // 34816 B
    struct { float h3t[16][260]; float wt[16][260]; float redq[256][17]; } q;
    struct { float h3l[512]; float redl[64][9]; float lbuf[VV]; } lg;
    struct { float ql[256]; float an[SS]; float r8[8]; } at;
  } u;
  float gates[32][18];
};

// ---------------------------------------------------------------- barrier --
__device__ __forceinline__ void gbar(unsigned* bar, int wg) {
  __syncthreads();
  if (threadIdx.x == 0) {
    __threadfence();
    unsigned* gc = bar + (wg >> 5) * 32;
    unsigned* gg = bar + 256 + (wg >> 5) * 32;
    unsigned* rc = bar + 512;
    unsigned* rg = bar + 544;
    unsigned g0 = __hip_atomic_load(gg, __ATOMIC_ACQUIRE, __HIP_MEMORY_SCOPE_AGENT);
    if (__hip_atomic_fetch_add(gc, 1u, __ATOMIC_ACQ_REL, __HIP_MEMORY_SCOPE_AGENT) == 31u) {
      unsigned r0 = __hip_atomic_load(rg, __ATOMIC_ACQUIRE, __HIP_MEMORY_SCOPE_AGENT);
      __hip_atomic_store(gc, 0u, __ATOMIC_RELAXED, __HIP_MEMORY_SCOPE_AGENT);
      if (__hip_atomic_fetch_add(rc, 1u, __ATOMIC_ACQ_REL, __HIP_MEMORY_SCOPE_AGENT) == 7u) {
        __hip_atomic_store(rc, 0u, __ATOMIC_RELAXED, __HIP_MEMORY_SCOPE_AGENT);
        __hip_atomic_fetch_add(rg, 1u, __ATOMIC_ACQ_REL, __HIP_MEMORY_SCOPE_AGENT);
      } else {
        while (__hip_atomic_load(rg, __ATOMIC_ACQUIRE, __HIP_MEMORY_SCOPE_AGENT) == r0)
          __builtin_amdgcn_s_sleep(2);
      }
      __hip_atomic_fetch_add(gg, 1u, __ATOMIC_ACQ_REL, __HIP_MEMORY_SCOPE_AGENT);
    } else {
      while (__hip_atomic_load(gg, __ATOMIC_ACQUIRE, __HIP_MEMORY_SCOPE_AGENT) == g0)
        __builtin_amdgcn_s_sleep(2);
    }
    __threadfence();
  }
  __syncthreads();
}

// ------------------------------------------------------------- LSTM stage -
// WG (cg = wg>>2, rg = wg&3): batches [rg*16,+16), hidden units [cg*8,+8).
// Gate-col gc in [0,32): global W row R = (gc&3)*512 + cg*8 + (gc>>2).
__device__ __forceinline__ void lstm_stage(
    SMem* sm, int wg, const float* __restrict__ xb,
    const float* __restrict__ Wih, const float* __restrict__ Whh,
    const float* __restrict__ bsum, float* cst, float* hd1, int o1,
    float* hd2, int o2) {
  const int tid = threadIdx.x;
  const int cg = wg >> 2, b0 = (wg & 3) * 16;
  const int rt = tid & 3, ct = (tid >> 2) & 7, ks = tid >> 5;
  const int srow = tid >> 5, sk4 = tid & 31;   // x staging
  float acc[4][4];
#pragma unroll
  for (int i = 0; i < 4; i++)
#pragma unroll
    for (int j = 0; j < 4; j++) acc[i][j] = 0.f;

  // stage chunk 0 into buf 0
  {
    *(float4*)&sm->u.s.xa[0][srow][sk4 * 4] =
        *(const float4*)&xb[(size_t)(b0 + srow) * 1024 + sk4 * 4];
#pragma unroll
    for (int i = 0; i < 2; i++) {
      int f4 = tid + i * 512;
      int wrow = f4 >> 5, k4 = f4 & 31;
      int R = ((wrow & 3) << 9) + (cg << 3) + (wrow >> 2);
      *(float4*)&sm->u.s.wa[0][wrow][k4 * 4] =
          *(const float4*)&Wih[(size_t)R * 512 + k4 * 4];
    }
  }
  __syncthreads();

  for (int c = 0; c < 8; c++) {
    const int cb = c & 1, nb = cb ^ 1;
    if (c < 7) {
      const int kc = c + 1;
      const int kg = kc * 128 + sk4 * 4;
      const float* xsrc = &xb[(size_t)(b0 + srow) * 1024 + kg];
      *(float4*)&sm->u.s.xa[nb][srow][sk4 * 4] = *(const float4*)xsrc;
#pragma unroll
      for (int i = 0; i < 2; i++) {
        int f4 = tid + i * 512;
        int wrow = f4 >> 5, k4 = f4 & 31;
        int R = ((wrow & 3) << 9) + (cg << 3) + (wrow >> 2);
        int kw = kc * 128 + k4 * 4;
        const float* src = (kw < 512) ? &Wih[(size_t)R * 512 + kw]
                                      : &Whh[(size_t)R * 512 + (kw - 512)];
        *(float4*)&sm->u.s.wa[nb][wrow][k4 * 4] = *(const float4*)src;
      }
    }
    // compute on buf cb
#pragma unroll
    for (int st = 0; st < 2; st++) {
      const int ko = (ks << 3) + (st << 2);
      float xr[4][4], wr[4][4];
#pragma unroll
      for (int i = 0; i < 4; i++) {
        float4 v = *(const float4*)&sm->u.s.xa[cb][(rt << 2) + i][ko];
        xr[i][0] = v.x; xr[i][1] = v.y; xr[i][2] = v.z; xr[i][3] = v.w;
      }
#pragma unroll
      for (int j = 0; j < 4; j++) {
        float4 v = *(const float4*)&sm->u.s.wa[cb][(j << 3) + ct][ko];
        wr[j][0] = v.x; wr[j][1] = v.y; wr[j][2] = v.z; wr[j][3] = v.w;
      }
#pragma unroll
      for (int i = 0; i < 4; i++)
#pragma unroll
        for (int j = 0; j < 4; j++)
#pragma unroll
          for (int k = 0; k < 4; k++)
            acc[i][j] = fmaf(xr[i][k], wr[j][k], acc[i][j]);
    }
    __syncthreads();
  }

  // K-partials -> LDS (union overlay of xa/wa; safe: sync above)
#pragma unroll
  for (int i = 0; i < 4; i++)
#pragma unroll
    for (int j = 0; j < 4; j++)
      sm->u.red[((j << 3) + ct) * 16 + (rt << 2) + i][ks] = acc[i][j];
  __syncthreads();
  {
    float s = 0.f;
#pragma unroll
    for (int k = 0; k < 16; k++) s += sm->u.red[tid][k];
    const int gc = tid >> 4, bl = tid & 15;
    const int R = ((gc & 3) << 9) + (cg << 3) + (gc >> 2);
    sm->gates[gc][bl] = s + bsum[R];
  }
  __syncthreads();
  if (tid < 128) {
    const int bl = tid & 15, jj = tid >> 4;
    const int b = b0 + bl, j = (cg << 3) + jj;
    const float gi = sm->gates[jj * 4 + 0][bl];
    const float gf = sm->gates[jj * 4 + 1][bl];
    const float gg = sm->gates[jj * 4 + 2][bl];
    const float go = sm->gates[jj * 4 + 3][bl];
    const float cold = cst[b * 512 + j];
    const float si = 1.f / (1.f + expf(-gi));
    const float sf = 1.f / (1.f + expf(-gf));
    const float so = 1.f / (1.f + expf(-go));
    const float cn = sf * cold + si * tanhf(gg);
    const float hn = so * tanhf(cn);
    cst[b * 512 + j] = cn;
    hd1[b * 1024 + o1 + j] = hn;
    if (hd2) hd2[b * 1024 + o2 + j] = hn;
  }
}

// --------------------------------------------------------------- Q stage --
__device__ __forceinline__ void q_stage(SMem* sm, int idx,
                                        const float* __restrict__ h3src,
                                        const float* __restrict__ Wq,
                                        const float* __restrict__ bq,
                                        float* qbuf) {
  const int tid = threadIdx.x;
  const int b0 = (idx & 3) * 16, c0 = (idx >> 2) * 16;
  const int bp = tid & 7, cg4 = (tid >> 3) & 3, ks = tid >> 5;
  float a4[2][4];
#pragma unroll
  for (int r = 0; r < 2; r++)
#pragma unroll
    for (int j = 0; j < 4; j++) a4[r][j] = 0.f;

  for (int ch = 0; ch < 2; ch++) {
#pragma unroll
    for (int i = 0; i < 2; i++) {
      int f4 = tid + i * 512;
      int row = f4 >> 6, k4 = f4 & 63;
      *(float4*)&sm->u.q.h3t[row][k4 * 4] =
          *(const float4*)&h3src[(size_t)(b0 + row) * 1024 + 512 + ch * 256 + k4 * 4];
      *(float4*)&sm->u.q.wt[row][k4 * 4] =
          *(const float4*)&Wq[(size_t)(c0 + row) * 512 + ch * 256 + k4 * 4];
    }
    __syncthreads();
#pragma unroll
    for (int kt = 0; kt < 4; kt++) {
      const int ko = ks * 16 + kt * 4;
      float xr[2][4], wr[4][4];
#pragma unroll
      for (int r = 0; r < 2; r++) {
        float4 v = *(const float4*)&sm->u.q.h3t[bp * 2 + r][ko];
        xr[r][0] = v.x; xr[r][1] = v.y; xr[r][2] = v.z; xr[r][3] = v.w;
      }
#pragma unroll
      for (int j = 0; j < 4; j++) {
        float4 v = *(const float4*)&sm->u.q.wt[cg4 * 4 + j][ko];
        wr[j][0] = v.x; wr[j][1] = v.y; wr[j][2] = v.z; wr[j][3] = v.w;
      }
#pragma unroll
      for (int r = 0; r < 2; r++)
#pragma unroll
        for (int j = 0; j < 4; j++)
#pragma unroll
          for (int k = 0; k < 4; k++)
            a4[r][j] = fmaf(xr[r][k], wr[j][k], a4[r][j]);
    }
    __syncthreads();
  }
#pragma unroll
  for (int r = 0; r < 2; r++)
#pragma unroll
    for (int j = 0; j < 4; j++)
      sm->u.q.redq[(cg4 * 4 + j) * 16 + bp * 2 + r][ks] = a4[r][j];
  __syncthreads();
  if (tid < 256) {
    const int c = tid >> 4, bl = tid & 15;
    float s = 0.f;
#pragma unroll
    for (int k = 0; k < 16; k++) s += sm->u.q.redq[tid][k];
    qbuf[(size_t)(b0 + bl) * KD + c0 + c] = s + bq[c0 + c];
  }
}

// ---------------------------------------------------- logits + NLL stage --
__device__ __forceinline__ void logits_stage(
    SMem* sm, int b, int t, const float* __restrict__ h3src,
    const float* __restrict__ WvT, const float* __restrict__ bv,
    const int* __restrict__ target, const float* __restrict__ tmask,
    float* lossacc) {
  const int tid = threadIdx.x;
  if (tid < 128)
    *(float4*)&sm->u.lg.h3l[tid * 4] =
        *(const float4*)&h3src[(size_t)b * 1024 + 512 + tid * 4];
  __syncthreads();
  const int c = tid & 63, ks = tid >> 6;
  float s = 0.f;
  if (c < VV) {
    for (int k = ks * 64; k < ks * 64 + 64; k++)
      s = fmaf(sm->u.lg.h3l[k], WvT[k * VV + c], s);
    sm->u.lg.redl[c][ks] = s;
  }
  __syncthreads();
  if (tid < VV) {
    float l = bv[tid];
#pragma unroll
    for (int k = 0; k < 8; k++) l += sm->u.lg.redl[tid][k];
    sm->u.lg.lbuf[tid] = l;
  }
  __syncthreads();
  if (tid == 0) {
    float M = sm->u.lg.lbuf[0];
    for (int v = 1; v < VV; v++) M = fmaxf(M, sm->u.lg.lbuf[v]);
    float Z = 0.f;
    for (int v = 0; v < VV; v++) Z += expf(sm->u.lg.lbuf[v] - M);
    const int yy = target[t * BB + b];
    const float nll = -(sm->u.lg.lbuf[yy] - M - logf(Z));
    lossacc[b] += tmask[t * BB + b] * nll;
  }
}

// ---------------------------------------------------------- attention -----
__device__ __forceinline__ void attn_stage(
    SMem* sm, int b, int t, const float* __restrict__ qbuf,
    const __half* __restrict__ keyT, const __half* __restrict__ val16,
    const float* __restrict__ amask, float* ctxdst, float* dout) {
  const int tid = threadIdx.x;
  if (tid < 64)
    *(float4*)&sm->u.at.ql[tid * 4] = *(const float4*)&qbuf[(size_t)b * KD + tid * 4];
  __syncthreads();
  float e = -1e30f;
  if (tid < SS) {
    float a = 0.f;
    const __half* kp = keyT + (size_t)b * KD * SS + tid;
#pragma unroll 8
    for (int k = 0; k < KD; k++) {
      a = fmaf(sm->u.at.ql[k], __half2float(*kp), a);
      kp += SS;
    }
    e = a;
  }
  float m = e;
  for (int o = 32; o; o >>= 1) m = fmaxf(m, __shfl_xor(m, o));
  if ((tid & 63) == 0) sm->u.at.r8[tid >> 6] = m;
  __syncthreads();
  m = sm->u.at.r8[0];
#pragma unroll
  for (int i = 1; i < 8; i++) m = fmaxf(m, sm->u.at.r8[i]);
  float p = (tid < SS) ? expf(e - m) : 0.f;
  float z = p;
  for (int o = 32; o; o >>= 1) z += __shfl_xor(z, o);
  __syncthreads();
  if ((tid & 63) == 0) sm->u.at.r8[tid >> 6] = z;
  __syncthreads();
  z = 0.f;
#pragma unroll
  for (int i = 0; i < 8; i++) z += sm->u.at.r8[i];
  const float attnv = p / z;
  if (b == 0 && tid < SS) dout[1 + (size_t)t * SS + tid] = attnv;
  float am = (tid < SS) ? attnv * amask[(size_t)b * SS + tid] : 0.f;
  float sa = fabsf(am);
  for (int o = 32; o; o >>= 1) sa += __shfl_xor(sa, o);
  __syncthreads();
  if ((tid & 63) == 0) sm->u.at.r8[tid >> 6] = sa;
  __syncthreads();
  sa = 0.f;
#pragma unroll
  for (int i = 0; i < 8; i++) sa += sm->u.at.r8[i];
  if (tid < SS) sm->u.at.an[tid] = am / fmaxf(sa, 1e-12f);
  __syncthreads();
  if (tid < KD) {
    float a = 0.f;
    const __half* vp = val16 + (size_t)b * SS * KD + tid;
#pragma unroll 4
    for (int s = 0; s < SS; s++) {
      a = fmaf(sm->u.at.an[s], __half2float(*vp), a);
      vp += KD;
    }
    ctxdst[(size_t)b * 1024 + 256 + tid] = a;
  }
}

// --------------------------------------------------------------- main -----
__global__ void __launch_bounds__(TPB, 1) kmain(
    const int* __restrict__ target, const float* __restrict__ tmask,
    const float* __restrict__ amask, const float* __restrict__ emb,
    const float* __restrict__ Wih1, const float* __restrict__ Whh1,
    const float* __restrict__ Wih2, const float* __restrict__ Whh2,
    const float* __restrict__ Wih3, const float* __restrict__ Whh3,
    const float* __restrict__ Wq, const float* __restrict__ bq,
    const float* __restrict__ bv, float* ws, const __half* __restrict__ keyT,
    const __half* __restrict__ val16, float* dout) {
  __shared__ SMem sm;
  const int wg = blockIdx.x, tid = threadIdx.x;
  unsigned* bar = (unsigned*)(ws + OFF_BAR);
  float* qb = ws + OFF_Q;
  float* lossacc = ws + OFF_LACC;

  for (int t = 0; t < NSTEP; t++) {
    const int cur = t & 1, nxt = cur ^ 1;
    float* X1c = ws + OFF_X1 + cur * 65536;
    float* X1n = ws + OFF_X1 + nxt * 65536;
    float* X2c = ws + OFF_X2 + cur * 65536;
    float* X2n = ws + OFF_X2 + nxt * 65536;
    float* X3c = ws + OFF_X3 + cur * 65536;
    float* X3n = ws + OFF_X3 + nxt * 65536;

    lstm_stage(&sm, wg, X1c, Wih1, Whh1, ws + OFF_BS1, ws + OFF_C1,
               X2c, 0, X1n, 512);
    gbar(bar, wg);
    lstm_stage(&sm, wg, X2c, Wih2, Whh2, ws + OFF_BS2, ws + OFF_C2,
               X3c, 0, X2n, 512);
    gbar(bar, wg);
    lstm_stage(&sm, wg, X3c, Wih3, Whh3, ws + OFF_BS3, ws + OFF_C3,
               X3n, 512, nullptr, 0);
    gbar(bar, wg);
    if (wg < 64) {
      if (t < TT)
        logits_stage(&sm, wg, t, X3n, ws + OFF_WVT, bv, target, tmask, lossacc);
    } else if (wg < 128) {
      q_stage(&sm, wg - 64, X3n, Wq, bq, qb);
    } else if (wg < 192) {
      const int b = wg - 128;
      if (t < TT) {
        const int y = target[t * BB + b];
        if (tid < 64)
          *(float4*)&X1n[(size_t)b * 1024 + tid * 4] =
              *(const float4*)&emb[(size_t)y * EE + tid * 4];
      }
    }
    gbar(bar, wg);
    if (wg < 64) attn_stage(&sm, wg, t, qb, keyT, val16, amask, X1n, dout);
    gbar(bar, wg);
  }
  if (wg == 0 && tid < 64) {
    float v = lossacc[tid];
    for (int o = 32; o; o >>= 1) v += __shfl_xor(v, o);
    if (tid == 0) dout[0] = v * (1.f / 64.f);
  }
}

// ---------------------------------------------------------------- init ----
__global__ void k_init(const float* emb, const float* Wq, const float* bq,
                       const float* Wv, const float* bih1, const float* bhh1,
                       const float* bih2, const float* bhh2, const float* bih3,
                       const float* bhh3, const float* hx1, const float* cx1,
                       const float* hx2, const float* cx2, const float* hx3,
                       const float* cx3, float* ws) {
  const int b = blockIdx.x, tid = threadIdx.x;
  float* X1 = ws + OFF_X1;
  float* X2 = ws + OFF_X2;
  float* X3 = ws + OFF_X3;
  __shared__ float hx[HH];
  for (int k = tid; k < HH; k += 256) {
    float v = hx1[k];
    hx[k] = v;
    X1[b * 1024 + 512 + k] = v;
    X2[b * 1024 + 512 + k] = hx2[k];
    X3[b * 1024 + 512 + k] = hx3[k];
    (ws + OFF_C1)[b * 512 + k] = cx1[k];
    (ws + OFF_C2)[b * 512 + k] = cx2[k];
    (ws + OFF_C3)[b * 512 + k] = cx3[k];
  }
  for (int k = tid; k < EE; k += 256) X1[b * 1024 + k] = emb[k];
  __syncthreads();
  for (int c = tid; c < KD; c += 256) {
    float a = bq[c];
    for (int k = 0; k < HH; k++) a = fmaf(hx[k], Wq[c * HH + k], a);
    X1[b * 1024 + 256 + c] = a;
  }
  if (b == 0) {
    for (int i = tid; i < 2048; i += 256) {
      (ws + OFF_BS1)[i] = bih1[i] + bhh1[i];
      (ws + OFF_BS2)[i] = bih2[i] + bhh2[i];
      (ws + OFF_BS3)[i] = bih3[i] + bhh3[i];
    }
    for (int i = tid; i < HH * VV; i += 256) {
      int h = i / VV, v = i % VV;
      (ws + OFF_WVT)[i] = Wv[v * HH + h];
    }
    if (tid < BB) (ws + OFF_LACC)[tid] = 0.f;
    unsigned* bar = (unsigned*)(ws + OFF_BAR);
    for (int i = tid; i < 1024; i += 256) bar[i] = 0u;
  }
}

// ------------------------------------------------- key/val fp16 staging ---
__global__ void k_cvt(const float* key, const float* val, __half* keyT16,
                      __half* val16) {
  const int blk = blockIdx.x, tid = threadIdx.x;
  if (blk < 4096) {
    const int b = blk >> 6;
    const int rem = blk & 63;
    const int k0 = (rem >> 3) * 32, s0 = (rem & 7) * 50;
    __shared__ float ld[50][33];
    for (int idx = tid; idx < 1600; idx += 256) {
      int si = idx >> 5, ki = idx & 31;
      ld[si][ki] = key[(size_t)b * SS * KD + (size_t)(s0 + si) * KD + k0 + ki];
    }
    __syncthreads();
    for (int idx = tid; idx < 1600; idx += 256) {
      int ki = idx / 50, si = idx % 50;
      keyT16[(size_t)b * KD * SS + (size_t)(k0 + ki) * SS + s0 + si] =
          __float2half(ld[si][ki]);
    }
  } else {
    const int base = (blk - 4096) * 3200;
    for (int j = 0; j < 13; ++j) {
      int i = base + tid + j * 256;
      if (i < BB * SS * KD) val16[i] = __float2half(val[i]);
    }
  }
}

// ------------------------------------------------------------ launch -----
extern "C" void kernel_launch(void* const* d_in, const int* in_sizes, int n_in,
                              void* d_out, int out_size, void* d_ws,
                              size_t ws_size, hipStream_t stream) {
  const int* target = (const int*)d_in[0];
  const float* tmask = (const float*)d_in[1];
  const float* key = (const float*)d_in[2];
  const float* val = (const float*)d_in[3];
  const float* amask = (const float*)d_in[4];
  const float* emb = (const float*)d_in[5];
  const float* Wih1 = (const float*)d_in[6];
  const float* Whh1 = (const float*)d_in[7];
  const float* bih1 = (const float*)d_in[8];
  const float* bhh1 = (const float*)d_in[9];
  const float* Wih2 = (const float*)d_in[10];
  const float* Whh2 = (const float*)d_in[11];
  const float* bih2 = (const float*)d_in[12];
  const float* bhh2 = (const float*)d_in[13];
  const float* Wih3 = (const float*)d_in[14];
  const float* Whh3 = (const float*)d_in[15];
  const float* bih3 = (const float*)d_in[16];
  const float* bhh3 = (const float*)d_in[17];
  const float* Wq = (const float*)d_in[18];
  const float* bq = (const float*)d_in[19];
  const float* Wv = (const float*)d_in[20];
  const float* bv = (const float*)d_in[21];
  const float* hx1 = (const float*)d_in[22];
  const float* cx1 = (const float*)d_in[23];
  const float* hx2 = (const float*)d_in[24];
  const float* cx2 = (const float*)d_in[25];
  const float* hx3 = (const float*)d_in[26];
  const float* cx3 = (const float*)d_in[27];
  float* out = (float*)d_out;
  float* ws = (float*)d_ws;
  __half* keyT16 = (__half*)((char*)d_ws + FP16_BYTE_OFF);
  __half* val16 = keyT16 + (size_t)BB * KD * SS;

  hipLaunchKernelGGL(k_init, dim3(64), dim3(256), 0, stream, emb, Wq, bq, Wv,
                     bih1, bhh1, bih2, bhh2, bih3, bhh3, hx1, cx1, hx2, cx2,
                     hx3, cx3, ws);
  hipLaunchKernelGGL(k_cvt, dim3(6144), dim3(256), 0, stream, key, val,
                     keyT16, val16);

  void* args[] = {(void*)&target, (void*)&tmask, (void*)&amask, (void*)&emb,
                  (void*)&Wih1,   (void*)&Whh1,  (void*)&Wih2,  (void*)&Whh2,
                  (void*)&Wih3,   (void*)&Whh3,  (void*)&Wq,    (void*)&bq,
                  (void*)&bv,     (void*)&ws,    (void*)&keyT16,
                  (void*)&val16,  (void*)&out};
  hipLaunchCooperativeKernel((const void*)kmain, dim3(NWG), dim3(TPB), args, 0,
                             stream);
}

// Round 3
// 19198.886 us; speedup vs baseline: 9.6968x; 9.6968x over previous
//
#include <hip/hip_runtime.h>
#include <hip/hip_fp16.h>

// SpellerModel round 3: stream-ordered multi-kernel (4 dispatches/step).
// k_lstm: 256 WGs x 256 thr, 16 batch x 32 gate-rows per WG, K=1024 in 8
// chunks of 128, 4x4 register tiles, XOR-swizzled LDS, double-buffered.
// k_fused: q (fp16 Wq) + attention + logits + nll + emb prefill, 64 WGs.

#define BB 64
#define TT 200
#define SS 400
#define VV 34
#define EE 256
#define HH 512
#define KD 256
#define NSTEP 201

// workspace float offsets (X buffers: [2][64][1024] ping-pong)
#define OFF_X1   0
#define OFF_X2   131072
#define OFF_X3   262144
#define OFF_C1   393216
#define OFF_C2   425984
#define OFF_C3   458752
#define OFF_LACC 507904
#define OFF_BS1  507968
#define OFF_BS2  510016
#define OFF_BS3  512064
#define OFF_WVT  514112
#define FP16_BYTE_OFF 2134016u
#define WQ16_BYTE_OFF (FP16_BYTE_OFF + 2u * 13107200u)

// ------------------------------------------------------------- LSTM ------
struct LstmS {
  union {
    struct { float xs[2][2048]; float wsd[2][4096]; } s;  // 48 KB staged tiles
    struct { float red[512 * 9]; float gb[512]; } r;      // 20 KB reduce
  };
};

__global__ __launch_bounds__(256) void k_lstm(
    const float* __restrict__ xb, const float* __restrict__ Wih,
    const float* __restrict__ Whh, const float* __restrict__ bsum,
    float* __restrict__ c_st, float* __restrict__ hd1, int o1,
    float* __restrict__ hd2, int o2) {
  __shared__ LstmS S;
  const int tid = threadIdx.x;
  const int cg = blockIdx.x & 63;        // hidden-unit group (XCD = cg%8)
  const int b0 = (blockIdx.x >> 6) * 16; // batch quarter
  // compute mapping
  const int rt = tid & 3, ct = (tid >> 2) & 7, ks = tid >> 5;
  // staging mapping
  const int sb = tid >> 4, sk0 = (tid & 15) * 2;
  const int wrow = tid >> 3, wk0 = (tid & 7) * 4;
  const int wR = ((wrow & 3) << 9) + (cg << 3) + (wrow >> 2);
  const int xk_s = sb & 7, wk_s = wrow & 7;

  int xbase[4], xkey[4];
#pragma unroll
  for (int i = 0; i < 4; i++) {
    const int bi = rt * 4 + i;
    xbase[i] = bi * 128;
    xkey[i] = bi & 7;
  }
  const int wbase = ct * 128, wkey = ct;

  float acc[4][4];
#pragma unroll
  for (int i = 0; i < 4; i++)
#pragma unroll
    for (int j = 0; j < 4; j++) acc[i][j] = 0.f;

  float4 xr0, xr1, wrg[4];
  const float* xrow = &xb[(size_t)(b0 + sb) * 1024];

#define LOAD_CHUNK(kc)                                                        \
  {                                                                           \
    xr0 = *(const float4*)&xrow[(kc)*128 + sk0 * 4];                          \
    xr1 = *(const float4*)&xrow[(kc)*128 + sk0 * 4 + 4];                      \
    const float* wp = ((kc) < 4) ? &Wih[(size_t)wR * 512 + (kc)*128]          \
                                 : &Whh[(size_t)wR * 512 + ((kc)-4) * 128];   \
    _Pragma("unroll") for (int m = 0; m < 4; m++)                             \
        wrg[m] = *(const float4*)&wp[(wk0 + m) * 4];                          \
  }
#define STORE_CHUNK(buf)                                                      \
  {                                                                           \
    *(float4*)&S.s.xs[buf][sb * 128 + ((sk0 ^ xk_s) << 2)] = xr0;             \
    *(float4*)&S.s.xs[buf][sb * 128 + (((sk0 + 1) ^ xk_s) << 2)] = xr1;       \
    _Pragma("unroll") for (int m = 0; m < 4; m++)                             \
        *(float4*)&S.s.wsd[buf][wrow * 128 + (((wk0 + m) ^ wk_s) << 2)] =     \
            wrg[m];                                                           \
  }

  LOAD_CHUNK(0);
  STORE_CHUNK(0);
  __syncthreads();

  for (int c = 0; c < 8; ++c) {
    const int cb = c & 1;
    if (c < 7) LOAD_CHUNK(c + 1);
#pragma unroll
    for (int st = 0; st < 4; ++st) {
      const int ko4 = (ks << 2) | st;
      float4 xv[4], wv[4];
#pragma unroll
      for (int i = 0; i < 4; i++)
        xv[i] = *(const float4*)&S.s.xs[cb][xbase[i] + ((ko4 ^ xkey[i]) << 2)];
#pragma unroll
      for (int j = 0; j < 4; j++)
        wv[j] = *(const float4*)&S.s
                     .wsd[cb][wbase + j * 1024 + ((ko4 ^ wkey) << 2)];
#pragma unroll
      for (int i = 0; i < 4; i++)
#pragma unroll
        for (int j = 0; j < 4; j++) {
          acc[i][j] = fmaf(xv[i].x, wv[j].x, acc[i][j]);
          acc[i][j] = fmaf(xv[i].y, wv[j].y, acc[i][j]);
          acc[i][j] = fmaf(xv[i].z, wv[j].z, acc[i][j]);
          acc[i][j] = fmaf(xv[i].w, wv[j].w, acc[i][j]);
        }
    }
    if (c < 7) STORE_CHUNK(cb ^ 1);
    __syncthreads();
  }

  // K-split reduction (overlay union; all compute reads synced above)
#pragma unroll
  for (int i = 0; i < 4; i++)
#pragma unroll
    for (int j = 0; j < 4; j++)
      S.r.red[((rt * 4 + i) * 32 + ct + 8 * j) * 9 + ks] = acc[i][j];
  __syncthreads();
#pragma unroll
  for (int o = tid; o < 512; o += 256) {
    float s = 0.f;
#pragma unroll
    for (int k = 0; k < 8; k++) s += S.r.red[o * 9 + k];
    const int r = o & 31;
    S.r.gb[o] = s + bsum[((r & 3) << 9) + (cg << 3) + (r >> 2)];
  }
  __syncthreads();
  if (tid < 128) {
    const int bl = tid & 15, uu = tid >> 4;
    const int gbase = bl * 32 + uu * 4;
    const float gi = S.r.gb[gbase + 0];
    const float gf = S.r.gb[gbase + 1];
    const float gG = S.r.gb[gbase + 2];
    const float go = S.r.gb[gbase + 3];
    const int b = b0 + bl, j = (cg << 3) + uu;
    const float cold = c_st[b * 512 + j];
    const float si = 1.f / (1.f + expf(-gi));
    const float sf = 1.f / (1.f + expf(-gf));
    const float so = 1.f / (1.f + expf(-go));
    const float cn = sf * cold + si * tanhf(gG);
    const float hn = so * tanhf(cn);
    c_st[b * 512 + j] = cn;
    hd1[(size_t)b * 1024 + o1 + j] = hn;
    if (hd2) hd2[(size_t)b * 1024 + o2 + j] = hn;
  }
#undef LOAD_CHUNK
#undef STORE_CHUNK
}

// -------------------------- fused q + attention + logits + nll + prefill --
__global__ __launch_bounds__(512) void k_fused(
    int t, const float* __restrict__ x3n, const __half* __restrict__ Wq16,
    const float* __restrict__ bqv, const __half* __restrict__ keyT,
    const __half* __restrict__ val16, const float* __restrict__ amask,
    const float* __restrict__ WvT, const float* __restrict__ bv,
    const int* __restrict__ target, const float* __restrict__ tmask,
    float* __restrict__ x1n, const float* __restrict__ emb, float* lossacc,
    float* __restrict__ dout) {
  const int b = blockIdx.x;
  const int tid = threadIdx.x;
  __shared__ float h3l[HH];
  __shared__ float qp[2][KD];
  __shared__ float qv[KD];
  __shared__ float an[SS];
  __shared__ float red[8];
  __shared__ float lbufp[4][VV];
  __shared__ float lbuf[VV];

  if (tid < 128)
    *(float4*)&h3l[tid * 4] =
        *(const float4*)&x3n[(size_t)b * 1024 + 512 + tid * 4];
  __syncthreads();

  // q = h3 @ Wq16.T + bq   (K split 2 over thread halves)
  {
    const int c = tid & 255, half = tid >> 8;
    const __half2* wp2 = (const __half2*)(Wq16 + (size_t)c * 512 + half * 256);
    const float* hp = &h3l[half * 256];
    float a = 0.f;
#pragma unroll 8
    for (int k = 0; k < 128; k++) {
      const float2 wf = __half22float2(wp2[k]);
      a = fmaf(hp[2 * k], wf.x, a);
      a = fmaf(hp[2 * k + 1], wf.y, a);
    }
    qp[half][c] = a;
  }
  __syncthreads();
  if (tid < KD) qv[tid] = qp[0][tid] + qp[1][tid] + bqv[tid];
  __syncthreads();

  // energy + softmax
  float e = -1e30f;
  if (tid < SS) {
    float a = 0.f;
    const __half* kp = keyT + (size_t)b * KD * SS + tid;
#pragma unroll 8
    for (int k = 0; k < KD; k++) {
      a = fmaf(qv[k], __half2float(*kp), a);
      kp += SS;
    }
    e = a;
  }
  float m = e;
  for (int o = 32; o; o >>= 1) m = fmaxf(m, __shfl_xor(m, o));
  if ((tid & 63) == 0) red[tid >> 6] = m;
  __syncthreads();
  m = red[0];
#pragma unroll
  for (int i = 1; i < 8; i++) m = fmaxf(m, red[i]);
  float p = (tid < SS) ? expf(e - m) : 0.f;
  float z = p;
  for (int o = 32; o; o >>= 1) z += __shfl_xor(z, o);
  __syncthreads();
  if ((tid & 63) == 0) red[tid >> 6] = z;
  __syncthreads();
  z = 0.f;
#pragma unroll
  for (int i = 0; i < 8; i++) z += red[i];
  const float attnv = p / z;
  if (b == 0 && tid < SS) dout[1 + (size_t)t * SS + tid] = attnv;
  // masked renormalize
  float am = (tid < SS) ? attnv * amask[(size_t)b * SS + tid] : 0.f;
  float sa = fabsf(am);
  for (int o = 32; o; o >>= 1) sa += __shfl_xor(sa, o);
  __syncthreads();
  if ((tid & 63) == 0) red[tid >> 6] = sa;
  __syncthreads();
  sa = 0.f;
#pragma unroll
  for (int i = 0; i < 8; i++) sa += red[i];
  if (tid < SS) an[tid] = am / fmaxf(sa, 1e-12f);
  __syncthreads();

  // ctx (threads 0..255) || logits partials (threads 256..511)
  if (tid < KD) {
    float a = 0.f;
    const __half* vp = val16 + (size_t)b * SS * KD + tid;
#pragma unroll 4
    for (int s = 0; s < SS; s++) {
      a = fmaf(an[s], __half2float(*vp), a);
      vp += KD;
    }
    x1n[(size_t)b * 1024 + 256 + tid] = a;
  } else if (t < TT) {
    const int lt = tid - 256;
    const int vv = lt & 63, hp = lt >> 6;
    if (vv < VV) {
      float a = 0.f;
      for (int h = hp * 128; h < hp * 128 + 128; h++)
        a = fmaf(h3l[h], WvT[h * VV + vv], a);
      lbufp[hp][vv] = a;
    }
  }
  __syncthreads();
  if (t < TT) {
    if (tid < VV)
      lbuf[tid] =
          bv[tid] + lbufp[0][tid] + lbufp[1][tid] + lbufp[2][tid] + lbufp[3][tid];
    __syncthreads();
    if (tid == 0) {
      float M = lbuf[0];
      for (int v = 1; v < VV; v++) M = fmaxf(M, lbuf[v]);
      float Z = 0.f;
      for (int v = 0; v < VV; v++) Z += expf(lbuf[v] - M);
      const int yy = target[t * BB + b];
      lossacc[b] += tmask[t * BB + b] * (-(lbuf[yy] - M - logf(Z)));
    }
    // emb prefill for step t+1 (token = target[t])
    if (tid >= 448) {
      const int y = target[t * BB + b];
      *(float4*)&x1n[(size_t)b * 1024 + (tid - 448) * 4] =
          *(const float4*)&emb[(size_t)y * EE + (tid - 448) * 4];
    }
  }
}

// ------------------------------------------------------------- loss ------
__global__ void k_loss(const float* lossacc, float* dout) {
  const int tid = threadIdx.x;
  float v = (tid < BB) ? lossacc[tid] : 0.f;
  for (int o = 32; o; o >>= 1) v += __shfl_xor(v, o);
  if (tid == 0) dout[0] = v * (1.f / 64.f);
}

// ---------------------------------------------------------------- init ----
__global__ void k_init(const float* emb, const float* Wq, const float* bq,
                       const float* Wv, const float* bih1, const float* bhh1,
                       const float* bih2, const float* bhh2, const float* bih3,
                       const float* bhh3, const float* hx1, const float* cx1,
                       const float* hx2, const float* cx2, const float* hx3,
                       const float* cx3, float* ws) {
  const int b = blockIdx.x, tid = threadIdx.x;
  float* X1 = ws + OFF_X1;
  float* X2 = ws + OFF_X2;
  float* X3 = ws + OFF_X3;
  __shared__ float hx[HH];
  for (int k = tid; k < HH; k += 256) {
    float v = hx1[k];
    hx[k] = v;
    X1[b * 1024 + 512 + k] = v;
    X2[b * 1024 + 512 + k] = hx2[k];
    X3[b * 1024 + 512 + k] = hx3[k];
    (ws + OFF_C1)[b * 512 + k] = cx1[k];
    (ws + OFF_C2)[b * 512 + k] = cx2[k];
    (ws + OFF_C3)[b * 512 + k] = cx3[k];
  }
  for (int k = tid; k < EE; k += 256) X1[b * 1024 + k] = emb[k];
  __syncthreads();
  for (int c = tid; c < KD; c += 256) {
    float a = bq[c];
    for (int k = 0; k < HH; k++) a = fmaf(hx[k], Wq[c * HH + k], a);
    X1[b * 1024 + 256 + c] = a;
  }
  if (b == 0) {
    for (int i = tid; i < 2048; i += 256) {
      (ws + OFF_BS1)[i] = bih1[i] + bhh1[i];
      (ws + OFF_BS2)[i] = bih2[i] + bhh2[i];
      (ws + OFF_BS3)[i] = bih3[i] + bhh3[i];
    }
    for (int i = tid; i < HH * VV; i += 256) {
      int h = i / VV, v = i % VV;
      (ws + OFF_WVT)[i] = Wv[v * HH + h];
    }
    if (tid < BB) (ws + OFF_LACC)[tid] = 0.f;
  }
}

// ------------------------------------------------- fp16 staging -----------
__global__ void k_cvt(const float* key, const float* val, const float* Wq,
                      __half* keyT16, __half* val16, __half* Wq16) {
  const int blk = blockIdx.x, tid = threadIdx.x;
  if (blk < 4096) {
    const int b = blk >> 6;
    const int rem = blk & 63;
    const int k0 = (rem >> 3) * 32, s0 = (rem & 7) * 50;
    __shared__ float ld[50][33];
    for (int idx = tid; idx < 1600; idx += 256) {
      int si = idx >> 5, ki = idx & 31;
      ld[si][ki] = key[(size_t)b * SS * KD + (size_t)(s0 + si) * KD + k0 + ki];
    }
    __syncthreads();
    for (int idx = tid; idx < 1600; idx += 256) {
      int ki = idx / 50, si = idx % 50;
      keyT16[(size_t)b * KD * SS + (size_t)(k0 + ki) * SS + s0 + si] =
          __float2half(ld[si][ki]);
    }
  } else if (blk < 6144) {
    const int base = (blk - 4096) * 3200;
    for (int j = 0; j < 13; ++j) {
      int i = base + tid + j * 256;
      if (i < BB * SS * KD) val16[i] = __float2half(val[i]);
    }
  } else {
    const int base = (blk - 6144) * 2048;
#pragma unroll
    for (int j = 0; j < 8; ++j) {
      int i = base + tid + j * 256;
      Wq16[i] = __float2half(Wq[i]);
    }
  }
}

// ------------------------------------------------------------ launch -----
extern "C" void kernel_launch(void* const* d_in, const int* in_sizes, int n_in,
                              void* d_out, int out_size, void* d_ws,
                              size_t ws_size, hipStream_t stream) {
  const int* target = (const int*)d_in[0];
  const float* tmask = (const float*)d_in[1];
  const float* key = (const float*)d_in[2];
  const float* val = (const float*)d_in[3];
  const float* amask = (const float*)d_in[4];
  const float* emb = (const float*)d_in[5];
  const float* Wih1 = (const float*)d_in[6];
  const float* Whh1 = (const float*)d_in[7];
  const float* bih1 = (const float*)d_in[8];
  const float* bhh1 = (const float*)d_in[9];
  const float* Wih2 = (const float*)d_in[10];
  const float* Whh2 = (const float*)d_in[11];
  const float* bih2 = (const float*)d_in[12];
  const float* bhh2 = (const float*)d_in[13];
  const float* Wih3 = (const float*)d_in[14];
  const float* Whh3 = (const float*)d_in[15];
  const float* bih3 = (const float*)d_in[16];
  const float* bhh3 = (const float*)d_in[17];
  const float* Wq = (const float*)d_in[18];
  const float* bq = (const float*)d_in[19];
  const float* Wv = (const float*)d_in[20];
  const float* bv = (const float*)d_in[21];
  const float* hx1 = (const float*)d_in[22];
  const float* cx1 = (const float*)d_in[23];
  const float* hx2 = (const float*)d_in[24];
  const float* cx2 = (const float*)d_in[25];
  const float* hx3 = (const float*)d_in[26];
  const float* cx3 = (const float*)d_in[27];
  float* out = (float*)d_out;
  float* ws = (float*)d_ws;
  __half* keyT16 = (__half*)((char*)d_ws + FP16_BYTE_OFF);
  __half* val16 = keyT16 + (size_t)BB * KD * SS;
  __half* Wq16 = (__half*)((char*)d_ws + WQ16_BYTE_OFF);
  float* lossacc = ws + OFF_LACC;

  hipLaunchKernelGGL(k_init, dim3(64), dim3(256), 0, stream, emb, Wq, bq, Wv,
                     bih1, bhh1, bih2, bhh2, bih3, bhh3, hx1, cx1, hx2, cx2,
                     hx3, cx3, ws);
  hipLaunchKernelGGL(k_cvt, dim3(6208), dim3(256), 0, stream, key, val, Wq,
                     keyT16, val16, Wq16);

  for (int t = 0; t < NSTEP; ++t) {
    const int cur = t & 1, nxt = cur ^ 1;
    float* X1c = ws + OFF_X1 + cur * 65536;
    float* X1n = ws + OFF_X1 + nxt * 65536;
    float* X2c = ws + OFF_X2 + cur * 65536;
    float* X2n = ws + OFF_X2 + nxt * 65536;
    float* X3c = ws + OFF_X3 + cur * 65536;
    float* X3n = ws + OFF_X3 + nxt * 65536;

    hipLaunchKernelGGL(k_lstm, dim3(256), dim3(256), 0, stream, X1c, Wih1,
                       Whh1, ws + OFF_BS1, ws + OFF_C1, X2c, 0, X1n, 512);
    hipLaunchKernelGGL(k_lstm, dim3(256), dim3(256), 0, stream, X2c, Wih2,
                       Whh2, ws + OFF_BS2, ws + OFF_C2, X3c, 0, X2n, 512);
    hipLaunchKernelGGL(k_lstm, dim3(256), dim3(256), 0, stream, X3c, Wih3,
                       Whh3, ws + OFF_BS3, ws + OFF_C3, X3n, 512, nullptr, 0);
    hipLaunchKernelGGL(k_fused, dim3(64), dim3(512), 0, stream, t, X3n, Wq16,
                       bq, keyT16, val16, amask, ws + OFF_WVT, bv, target,
                       tmask, X1n, emb, lossacc, out);
  }
  hipLaunchKernelGGL(k_loss, dim3(1), dim3(64), 0, stream, lossacc, out);
}

// Round 4
// 18946.898 us; speedup vs baseline: 9.8257x; 1.0133x over previous
//
#include <hip/hip_runtime.h>
#include <hip/hip_fp16.h>

// SpellerModel round 4: stream-ordered 4 dispatches/step, occupancy-fixed.
// k_lstm: 512 WGs x 256 thr (2 WG/CU), 16b x 16g tile, K-split 4 (1 slice
// per wave), 2x2 reg tiles, XOR-swizzled LDS, double-buffered chunks.
// k_fused: 1024 thr, q/energy/ctx loops split across 2-4x threads.

#define BB 64
#define TT 200
#define SS 400
#define VV 34
#define EE 256
#define HH 512
#define KD 256
#define NSTEP 201

// workspace float offsets (X buffers: [2][64][1024] ping-pong)
#define OFF_X1   0
#define OFF_X2   131072
#define OFF_X3   262144
#define OFF_C1   393216
#define OFF_C2   425984
#define OFF_C3   458752
#define OFF_LACC 507904
#define OFF_BS1  507968
#define OFF_BS2  510016
#define OFF_BS3  512064
#define OFF_WVT  514112
#define FP16_BYTE_OFF 2134016u
#define WQ16_BYTE_OFF (FP16_BYTE_OFF + 2u * 13107200u)

// ------------------------------------------------------------- LSTM ------
struct LstmS {
  union {
    struct { float xs[2][2048]; float wsd[2][2048]; } s;  // 32 KB tiles
    struct { float red[256][5]; float gb[256]; } r;       // reduce overlay
  };
};

__global__ __launch_bounds__(256, 2) void k_lstm(
    const float* __restrict__ xb, const float* __restrict__ Wih,
    const float* __restrict__ Whh, const float* __restrict__ bsum,
    float* __restrict__ c_st, float* __restrict__ hd1, int o1,
    float* __restrict__ hd2, int o2) {
  __shared__ LstmS S;
  const int tid = threadIdx.x;
  const int cg = blockIdx.x & 127;        // 4 hidden units (16 gate rows)
  const int b0 = (blockIdx.x >> 7) * 16;  // batch quarter
  // compute mapping: 2x2 out tile, K-slice per wave
  const int rt = tid & 7, ct = (tid >> 3) & 7, ks = tid >> 6;
  // staging mapping: 16 rows x 16 col-groups (8 floats each)
  const int sb = tid >> 4, sk = tid & 15;
  const int wR = ((sb & 3) << 9) + (cg << 2) + (sb >> 2);
  const int xkey = sb & 7;

  float a00 = 0.f, a01 = 0.f, a10 = 0.f, a11 = 0.f;
  float4 xr0, xr1, wv0, wv1;
  const float* xrow = &xb[(size_t)(b0 + sb) * 1024];

#define LOAD_CHUNK(kc)                                                        \
  {                                                                           \
    xr0 = *(const float4*)&xrow[(kc)*128 + sk * 8];                           \
    xr1 = *(const float4*)&xrow[(kc)*128 + sk * 8 + 4];                       \
    const float* wp = ((kc) < 4)                                              \
                          ? &Wih[(size_t)wR * 512 + (kc)*128 + sk * 8]        \
                          : &Whh[(size_t)wR * 512 + ((kc)-4) * 128 + sk * 8]; \
    wv0 = *(const float4*)&wp[0];                                             \
    wv1 = *(const float4*)&wp[4];                                             \
  }
#define STORE_CHUNK(buf)                                                      \
  {                                                                           \
    *(float4*)&S.s.xs[buf][sb * 128 + (((sk * 2) ^ xkey) << 2)] = xr0;        \
    *(float4*)&S.s.xs[buf][sb * 128 + (((sk * 2 + 1) ^ xkey) << 2)] = xr1;    \
    *(float4*)&S.s.wsd[buf][sb * 128 + (((sk * 2) ^ xkey) << 2)] = wv0;       \
    *(float4*)&S.s.wsd[buf][sb * 128 + (((sk * 2 + 1) ^ xkey) << 2)] = wv1;   \
  }

  LOAD_CHUNK(0);
  STORE_CHUNK(0);
  __syncthreads();

  const int xb0 = (2 * rt) * 128, xk0 = (2 * rt) & 7;
  const int xb1 = (2 * rt + 1) * 128, xk1 = (2 * rt + 1) & 7;
  const int wb0 = (2 * ct) * 128, wk0 = (2 * ct) & 7;
  const int wb1 = (2 * ct + 1) * 128, wk1 = (2 * ct + 1) & 7;

  for (int c = 0; c < 8; ++c) {
    const int cb = c & 1;
    if (c < 7) LOAD_CHUNK(c + 1);
#pragma unroll
    for (int kk = 0; kk < 8; ++kk) {
      const int k4 = (ks << 3) + kk;
      const float4 x0 = *(const float4*)&S.s.xs[cb][xb0 + ((k4 ^ xk0) << 2)];
      const float4 x1 = *(const float4*)&S.s.xs[cb][xb1 + ((k4 ^ xk1) << 2)];
      const float4 w0 = *(const float4*)&S.s.wsd[cb][wb0 + ((k4 ^ wk0) << 2)];
      const float4 w1 = *(const float4*)&S.s.wsd[cb][wb1 + ((k4 ^ wk1) << 2)];
      a00 = fmaf(x0.x, w0.x, a00); a00 = fmaf(x0.y, w0.y, a00);
      a00 = fmaf(x0.z, w0.z, a00); a00 = fmaf(x0.w, w0.w, a00);
      a01 = fmaf(x0.x, w1.x, a01); a01 = fmaf(x0.y, w1.y, a01);
      a01 = fmaf(x0.z, w1.z, a01); a01 = fmaf(x0.w, w1.w, a01);
      a10 = fmaf(x1.x, w0.x, a10); a10 = fmaf(x1.y, w0.y, a10);
      a10 = fmaf(x1.z, w0.z, a10); a10 = fmaf(x1.w, w0.w, a10);
      a11 = fmaf(x1.x, w1.x, a11); a11 = fmaf(x1.y, w1.y, a11);
      a11 = fmaf(x1.z, w1.z, a11); a11 = fmaf(x1.w, w1.w, a11);
    }
    if (c < 7) STORE_CHUNK(cb ^ 1);
    __syncthreads();
  }

  // K-slice partials -> LDS (overlay; all tile reads synced above)
  S.r.red[(2 * ct + 0) * 16 + 2 * rt + 0][ks] = a00;
  S.r.red[(2 * ct + 1) * 16 + 2 * rt + 0][ks] = a01;
  S.r.red[(2 * ct + 0) * 16 + 2 * rt + 1][ks] = a10;
  S.r.red[(2 * ct + 1) * 16 + 2 * rt + 1][ks] = a11;
  __syncthreads();
  {
    const float s =
        S.r.red[tid][0] + S.r.red[tid][1] + S.r.red[tid][2] + S.r.red[tid][3];
    const int col = tid >> 4;
    S.r.gb[tid] = s + bsum[((col & 3) << 9) + (cg << 2) + (col >> 2)];
  }
  __syncthreads();
  if (tid < 64) {
    const int bl = tid & 15, u = tid >> 4;
    const float gi = S.r.gb[(u * 4 + 0) * 16 + bl];
    const float gf = S.r.gb[(u * 4 + 1) * 16 + bl];
    const float gG = S.r.gb[(u * 4 + 2) * 16 + bl];
    const float go = S.r.gb[(u * 4 + 3) * 16 + bl];
    const int b = b0 + bl, j = (cg << 2) + u;
    const float cold = c_st[b * 512 + j];
    const float si = 1.f / (1.f + expf(-gi));
    const float sf = 1.f / (1.f + expf(-gf));
    const float so = 1.f / (1.f + expf(-go));
    const float cn = sf * cold + si * tanhf(gG);
    const float hn = so * tanhf(cn);
    c_st[b * 512 + j] = cn;
    hd1[(size_t)b * 1024 + o1 + j] = hn;
    if (hd2) hd2[(size_t)b * 1024 + o2 + j] = hn;
  }
#undef LOAD_CHUNK
#undef STORE_CHUNK
}

// -------------------------- fused q + attention + logits + nll + prefill --
__global__ __launch_bounds__(1024) void k_fused(
    int t, const float* __restrict__ x3n, const __half* __restrict__ Wq16,
    const float* __restrict__ bqv, const __half* __restrict__ keyT,
    const __half* __restrict__ val16, const float* __restrict__ amask,
    const float* __restrict__ WvT, const float* __restrict__ bv,
    const int* __restrict__ target, const float* __restrict__ tmask,
    float* __restrict__ x1n, const float* __restrict__ emb, float* lossacc,
    float* __restrict__ dout) {
  const int b = blockIdx.x;
  const int tid = threadIdx.x;
  __shared__ float h3l[HH];
  __shared__ float qp[2][KD];
  __shared__ float qv[KD];
  __shared__ float esum[2][SS];
  __shared__ float an[SS];
  __shared__ float red[16];
  __shared__ float cxp[3][KD];
  __shared__ float lbufp[4][VV];
  __shared__ float lbuf[VV];

  if (tid < 128)
    *(float4*)&h3l[tid * 4] =
        *(const float4*)&x3n[(size_t)b * 1024 + 512 + tid * 4];
  __syncthreads();

  // q = h3 @ Wq16.T + bq   (c x K-half over 512 threads)
  if (tid < 512) {
    const int c = tid >> 1, kh = tid & 1;
    const __half2* wp2 = (const __half2*)(Wq16 + (size_t)c * 512 + kh * 256);
    const float* hp = &h3l[kh * 256];
    float a = 0.f;
#pragma unroll 8
    for (int k = 0; k < 128; k++) {
      const float2 wf = __half22float2(wp2[k]);
      a = fmaf(hp[2 * k], wf.x, a);
      a = fmaf(hp[2 * k + 1], wf.y, a);
    }
    qp[kh][c] = a;
  }
  __syncthreads();
  if (tid < KD) qv[tid] = qp[0][tid] + qp[1][tid] + bqv[tid];
  __syncthreads();

  // energy (s x K-half over 800 threads)
  if (tid < 800) {
    const int s = tid >> 1, kh = tid & 1;
    const __half* kp = keyT + (size_t)b * KD * SS + (size_t)(kh * 128) * SS + s;
    const float* qh = &qv[kh * 128];
    float a = 0.f;
#pragma unroll 8
    for (int k = 0; k < 128; k++) {
      a = fmaf(qh[k], __half2float(*kp), a);
      kp += SS;
    }
    esum[kh][s] = a;
  }
  __syncthreads();
  float e = -1e30f;
  if (tid < SS) e = esum[0][tid] + esum[1][tid];
  float m = e;
  for (int o = 32; o; o >>= 1) m = fmaxf(m, __shfl_xor(m, o));
  if ((tid & 63) == 0) red[tid >> 6] = m;
  __syncthreads();
  m = red[0];
#pragma unroll
  for (int i = 1; i < 16; i++) m = fmaxf(m, red[i]);
  float p = (tid < SS) ? expf(e - m) : 0.f;
  float z = p;
  for (int o = 32; o; o >>= 1) z += __shfl_xor(z, o);
  __syncthreads();
  if ((tid & 63) == 0) red[tid >> 6] = z;
  __syncthreads();
  z = 0.f;
#pragma unroll
  for (int i = 0; i < 16; i++) z += red[i];
  const float attnv = p / z;
  if (b == 0 && tid < SS) dout[1 + (size_t)t * SS + tid] = attnv;
  // masked renormalize
  float am = (tid < SS) ? attnv * amask[(size_t)b * SS + tid] : 0.f;
  float sa = fabsf(am);
  for (int o = 32; o; o >>= 1) sa += __shfl_xor(sa, o);
  __syncthreads();
  if ((tid & 63) == 0) red[tid >> 6] = sa;
  __syncthreads();
  sa = 0.f;
#pragma unroll
  for (int i = 0; i < 16; i++) sa += red[i];
  if (tid < SS) an[tid] = am / fmaxf(sa, 1e-12f);
  __syncthreads();

  // ctx (768 thr: k x 3 s-thirds) || logits (vv<34 of 768+) || emb prefill
  if (tid < 768) {
    const int k = tid & 255, sq = tid >> 8;
    const int s0 = (sq == 0) ? 0 : 1 + 133 * sq;  // 0, 134, 267
    const int sn = (sq == 0) ? 134 : 133;
    const __half* vp = val16 + (size_t)b * SS * KD + (size_t)s0 * KD + k;
    float a = 0.f;
#pragma unroll 4
    for (int i = 0; i < sn; i++) {
      a = fmaf(an[s0 + i], __half2float(*vp), a);
      vp += KD;
    }
    cxp[sq][k] = a;
  } else if (t < TT) {
    const int lt = tid - 768;
    const int vv = lt & 63, hp = lt >> 6;
    if (vv < VV) {
      float a = 0.f;
      const int h0 = hp * 128;
      for (int h = h0; h < h0 + 128; h++) a = fmaf(h3l[h], WvT[h * VV + vv], a);
      lbufp[hp][vv] = a;
    } else if (vv >= 48) {
      const int y = target[t * BB + b];
      const int idx = hp * 16 + (vv - 48);
      *(float4*)&x1n[(size_t)b * 1024 + idx * 4] =
          *(const float4*)&emb[(size_t)y * EE + idx * 4];
    }
  }
  __syncthreads();
  if (tid < KD)
    x1n[(size_t)b * 1024 + 256 + tid] = cxp[0][tid] + cxp[1][tid] + cxp[2][tid];
  if (t < TT && tid < VV)
    lbuf[tid] =
        bv[tid] + lbufp[0][tid] + lbufp[1][tid] + lbufp[2][tid] + lbufp[3][tid];
  __syncthreads();
  if (t < TT && tid == 0) {
    float M = lbuf[0];
    for (int v = 1; v < VV; v++) M = fmaxf(M, lbuf[v]);
    float Z = 0.f;
    for (int v = 0; v < VV; v++) Z += expf(lbuf[v] - M);
    const int yy = target[t * BB + b];
    lossacc[b] += tmask[t * BB + b] * (-(lbuf[yy] - M - logf(Z)));
  }
}

// ------------------------------------------------------------- loss ------
__global__ void k_loss(const float* lossacc, float* dout) {
  const int tid = threadIdx.x;
  float v = (tid < BB) ? lossacc[tid] : 0.f;
  for (int o = 32; o; o >>= 1) v += __shfl_xor(v, o);
  if (tid == 0) dout[0] = v * (1.f / 64.f);
}

// ---------------------------------------------------------------- init ----
__global__ void k_init(const float* emb, const float* Wq, const float* bq,
                       const float* Wv, const float* bih1, const float* bhh1,
                       const float* bih2, const float* bhh2, const float* bih3,
                       const float* bhh3, const float* hx1, const float* cx1,
                       const float* hx2, const float* cx2, const float* hx3,
                       const float* cx3, float* ws) {
  const int b = blockIdx.x, tid = threadIdx.x;
  float* X1 = ws + OFF_X1;
  float* X2 = ws + OFF_X2;
  float* X3 = ws + OFF_X3;
  __shared__ float hx[HH];
  for (int k = tid; k < HH; k += 256) {
    float v = hx1[k];
    hx[k] = v;
    X1[b * 1024 + 512 + k] = v;
    X2[b * 1024 + 512 + k] = hx2[k];
    X3[b * 1024 + 512 + k] = hx3[k];
    (ws + OFF_C1)[b * 512 + k] = cx1[k];
    (ws + OFF_C2)[b * 512 + k] = cx2[k];
    (ws + OFF_C3)[b * 512 + k] = cx3[k];
  }
  for (int k = tid; k < EE; k += 256) X1[b * 1024 + k] = emb[k];
  __syncthreads();
  for (int c = tid; c < KD; c += 256) {
    float a = bq[c];
    for (int k = 0; k < HH; k++) a = fmaf(hx[k], Wq[c * HH + k], a);
    X1[b * 1024 + 256 + c] = a;
  }
  if (b == 0) {
    for (int i = tid; i < 2048; i += 256) {
      (ws + OFF_BS1)[i] = bih1[i] + bhh1[i];
      (ws + OFF_BS2)[i] = bih2[i] + bhh2[i];
      (ws + OFF_BS3)[i] = bih3[i] + bhh3[i];
    }
    for (int i = tid; i < HH * VV; i += 256) {
      int h = i / VV, v = i % VV;
      (ws + OFF_WVT)[i] = Wv[v * HH + h];
    }
    if (tid < BB) (ws + OFF_LACC)[tid] = 0.f;
  }
}

// ------------------------------------------------- fp16 staging -----------
__global__ void k_cvt(const float* key, const float* val, const float* Wq,
                      __half* keyT16, __half* val16, __half* Wq16) {
  const int blk = blockIdx.x, tid = threadIdx.x;
  if (blk < 4096) {
    const int b = blk >> 6;
    const int rem = blk & 63;
    const int k0 = (rem >> 3) * 32, s0 = (rem & 7) * 50;
    __shared__ float ld[50][33];
    for (int idx = tid; idx < 1600; idx += 256) {
      int si = idx >> 5, ki = idx & 31;
      ld[si][ki] = key[(size_t)b * SS * KD + (size_t)(s0 + si) * KD + k0 + ki];
    }
    __syncthreads();
    for (int idx = tid; idx < 1600; idx += 256) {
      int ki = idx / 50, si = idx % 50;
      keyT16[(size_t)b * KD * SS + (size_t)(k0 + ki) * SS + s0 + si] =
          __float2half(ld[si][ki]);
    }
  } else if (blk < 6144) {
    const int base = (blk - 4096) * 3200;
    for (int j = 0; j < 13; ++j) {
      int i = base + tid + j * 256;
      if (i < BB * SS * KD) val16[i] = __float2half(val[i]);
    }
  } else {
    const int base = (blk - 6144) * 2048;
#pragma unroll
    for (int j = 0; j < 8; ++j) {
      int i = base + tid + j * 256;
      Wq16[i] = __float2half(Wq[i]);
    }
  }
}

// ------------------------------------------------------------ launch -----
extern "C" void kernel_launch(void* const* d_in, const int* in_sizes, int n_in,
                              void* d_out, int out_size, void* d_ws,
                              size_t ws_size, hipStream_t stream) {
  const int* target = (const int*)d_in[0];
  const float* tmask = (const float*)d_in[1];
  const float* key = (const float*)d_in[2];
  const float* val = (const float*)d_in[3];
  const float* amask = (const float*)d_in[4];
  const float* emb = (const float*)d_in[5];
  const float* Wih1 = (const float*)d_in[6];
  const float* Whh1 = (const float*)d_in[7];
  const float* bih1 = (const float*)d_in[8];
  const float* bhh1 = (const float*)d_in[9];
  const float* Wih2 = (const float*)d_in[10];
  const float* Whh2 = (const float*)d_in[11];
  const float* bih2 = (const float*)d_in[12];
  const float* bhh2 = (const float*)d_in[13];
  const float* Wih3 = (const float*)d_in[14];
  const float* Whh3 = (const float*)d_in[15];
  const float* bih3 = (const float*)d_in[16];
  const float* bhh3 = (const float*)d_in[17];
  const float* Wq = (const float*)d_in[18];
  const float* bq = (const float*)d_in[19];
  const float* Wv = (const float*)d_in[20];
  const float* bv = (const float*)d_in[21];
  const float* hx1 = (const float*)d_in[22];
  const float* cx1 = (const float*)d_in[23];
  const float* hx2 = (const float*)d_in[24];
  const float* cx2 = (const float*)d_in[25];
  const float* hx3 = (const float*)d_in[26];
  const float* cx3 = (const float*)d_in[27];
  float* out = (float*)d_out;
  float* ws = (float*)d_ws;
  __half* keyT16 = (__half*)((char*)d_ws + FP16_BYTE_OFF);
  __half* val16 = keyT16 + (size_t)BB * KD * SS;
  __half* Wq16 = (__half*)((char*)d_ws + WQ16_BYTE_OFF);
  float* lossacc = ws + OFF_LACC;

  hipLaunchKernelGGL(k_init, dim3(64), dim3(256), 0, stream, emb, Wq, bq, Wv,
                     bih1, bhh1, bih2, bhh2, bih3, bhh3, hx1, cx1, hx2, cx2,
                     hx3, cx3, ws);
  hipLaunchKernelGGL(k_cvt, dim3(6208), dim3(256), 0, stream, key, val, Wq,
                     keyT16, val16, Wq16);

  for (int t = 0; t < NSTEP; ++t) {
    const int cur = t & 1, nxt = cur ^ 1;
    float* X1c = ws + OFF_X1 + cur * 65536;
    float* X1n = ws + OFF_X1 + nxt * 65536;
    float* X2c = ws + OFF_X2 + cur * 65536;
    float* X2n = ws + OFF_X2 + nxt * 65536;
    float* X3c = ws + OFF_X3 + cur * 65536;
    float* X3n = ws + OFF_X3 + nxt * 65536;

    hipLaunchKernelGGL(k_lstm, dim3(512), dim3(256), 0, stream, X1c, Wih1,
                       Whh1, ws + OFF_BS1, ws + OFF_C1, X2c, 0, X1n, 512);
    hipLaunchKernelGGL(k_lstm, dim3(512), dim3(256), 0, stream, X2c, Wih2,
                       Whh2, ws + OFF_BS2, ws + OFF_C2, X3c, 0, X2n, 512);
    hipLaunchKernelGGL(k_lstm, dim3(512), dim3(256), 0, stream, X3c, Wih3,
                       Whh3, ws + OFF_BS3, ws + OFF_C3, X3n, 512, nullptr, 0);
    hipLaunchKernelGGL(k_fused, dim3(64), dim3(1024), 0, stream, t, X3n, Wq16,
                       bq, keyT16, val16, amask, ws + OFF_WVT, bv, target,
                       tmask, X1n, emb, lossacc, out);
  }
  hipLaunchKernelGGL(k_loss, dim3(1), dim3(64), 0, stream, lossacc, out);
}